// Round 10
// baseline (28.086 us; speedup 1.0000x reference)
//
#include <hip/hip_runtime.h>

// Logm of 2*2^20 independent 3x3 SPD matrices — closed-form eigenvalues.
// Layout: x[b][c][v], c = 3*i+j, plane stride NV = 2^20 floats.
// Input is bit-symmetric -> read only upper-triangle planes {0,1,2,4,5,8}.
// 2-stage software pipeline per thread: voxel pair v=2t of batch 0 AND the
// same pair of batch 1. All 12 float2 loads issued up front (stage-B HBM
// latency hides under stage-A compute; stage-A stores drain under stage-B
// compute). ~50 live regs -> under the 64-VGPR cliff -> 32 waves/CU.
// Per voxel: char-poly -> Cardano trig eigenvalues -> Newton divided
// differences: log(M) = k0*I + k1*M + k2*M^2 (passed r8/r9).

#define NV (1 << 20)   // D*H*W
#define BT 2

__device__ __forceinline__ float rcpf(float x) { return __builtin_amdgcn_rcpf(x); }

__device__ __forceinline__ void logm3(
    float a00, float a01, float a02, float a11, float a12, float a22,
    float &y00, float &y01, float &y02, float &y11, float &y12, float &y22)
{
    const float THIRD = 0.33333333333f;
    float m   = (a00 + a11 + a22) * THIRD;
    float b00 = a00 - m, b11 = a11 - m, b22 = a22 - m;
    float off2  = fmaf(a01, a01, fmaf(a02, a02, a12 * a12));
    float diag2 = fmaf(b00, b00, fmaf(b11, b11, b22 * b22));
    float p2 = fmaf(diag2, 1.0f / 6.0f, off2 * THIRD);   // p = tr(B^2)/6
    float sp = sqrtf(p2);
    float detB = b00 * fmaf(b11, b22, -a12 * a12)
               - a01 * fmaf(a01, b22, -a12 * a02)
               + a02 * fmaf(a01, a12, -b11 * a02);
    float q  = 0.5f * detB;
    float rr = q * rcpf(fmaxf(p2 * sp, 1e-30f));         // q / p^(3/2)
    rr = fminf(fmaxf(rr, -1.0f), 1.0f);

    // acos(rr): deg-7 poly on |rr|, reflect for rr<0  (|err| ~ 7e-8 rad)
    float ar  = fabsf(rr);
    float acp = fmaf(ar, fmaf(ar, fmaf(ar, fmaf(ar, fmaf(ar, fmaf(ar, fmaf(ar,
        -0.0012624911f, 0.0066700901f), -0.0170881256f), 0.0308918810f),
        -0.0501743046f), 0.0889789874f), -0.2145988016f), 1.5707963050f);
    float A   = sqrtf(fmaxf(1.0f - ar, 0.0f)) * acp;
    float phi = (rr >= 0.0f) ? A : (3.14159265359f - A);
    float th  = phi * THIRD;                              // [0, pi/3]

    float c0  = __cosf(th);
    float s0  = sqrtf(fmaxf(fmaf(-c0, c0, 1.0f), 0.0f));
    float cm  = -0.5f * c0;
    float c1  = fmaf(-0.86602540378f, s0, cm);            // -> min
    float c2c = fmaf( 0.86602540378f, s0, cm);            // -> mid
    float tsp = 2.0f * sp;
    float L1 = fmaf(tsp, c0,  m);                         // max
    float L2 = fmaf(tsp, c2c, m);                         // mid
    float L3 = fmaf(tsp, c1,  m);                         // min

    float g1 = __logf(L1), g2 = __logf(L2), g3 = __logf(L3);

    float d12 = L1 - L2, d23 = L2 - L3;
    float d13 = fmaxf(L1 - L3, 1e-6f);
    float i2  = rcpf(L2), i3 = rcpf(L3);
    float x12 = d12 * i2, x23 = d23 * i3;
    float s12 = fmaf(x12, fmaf(x12, fmaf(x12, -0.25f, THIRD), -0.5f), 1.0f);
    float s23 = fmaf(x23, fmaf(x23, fmaf(x23, -0.25f, THIRD), -0.5f), 1.0f);
    float f12 = (x12 < 0.03f) ? s12 * i2 : (g1 - g2) * rcpf(fmaxf(d12, 1e-30f));
    float f23 = (x23 < 0.03f) ? s23 * i3 : (g2 - g3) * rcpf(fmaxf(d23, 1e-30f));
    float cc2 = (f12 - f23) * rcpf(d13);

    float k0 = fmaf(cc2, L1 * L2, fmaf(-f12, L1, g1));
    float k1 = fmaf(-cc2, L1 + L2, f12);

    float s00  = fmaf(a00, a00, fmaf(a01, a01, a02 * a02));
    float s11  = fmaf(a01, a01, fmaf(a11, a11, a12 * a12));
    float s22  = fmaf(a02, a02, fmaf(a12, a12, a22 * a22));
    float s01  = fmaf(a01, a00 + a11, a02 * a12);
    float s02  = fmaf(a02, a00 + a22, a01 * a12);
    float s12m = fmaf(a12, a11 + a22, a01 * a02);

    y00 = fmaf(cc2, s00,  fmaf(k1, a00, k0));
    y11 = fmaf(cc2, s11,  fmaf(k1, a11, k0));
    y22 = fmaf(cc2, s22,  fmaf(k1, a22, k0));
    y01 = fmaf(cc2, s01,  k1 * a01);
    y02 = fmaf(cc2, s02,  k1 * a02);
    y12 = fmaf(cc2, s12m, k1 * a12);
}

// compute 2 voxels from 6 float2 inputs and store 9 float2 planes
__device__ __forceinline__ void stage(const float2 A[6], float* yb)
{
    float O00[2], O01[2], O02[2], O11[2], O12[2], O22[2];
#pragma unroll
    for (int j = 0; j < 2; ++j) {
        float a00 = j ? A[0].y : A[0].x;
        float a01 = j ? A[1].y : A[1].x;
        float a02 = j ? A[2].y : A[2].x;
        float a11 = j ? A[3].y : A[3].x;
        float a12 = j ? A[4].y : A[4].x;
        float a22 = j ? A[5].y : A[5].x;
        logm3(a00, a01, a02, a11, a12, a22,
              O00[j], O01[j], O02[j], O11[j], O12[j], O22[j]);
    }
    float2 W;
#define STORE(ch, arr) \
    W.x = arr[0]; W.y = arr[1]; \
    *reinterpret_cast<float2*>(yb + (size_t)(ch) * NV) = W;
    STORE(0, O00) STORE(1, O01) STORE(2, O02)
    STORE(3, O01) STORE(4, O11) STORE(5, O12)
    STORE(6, O02) STORE(7, O12) STORE(8, O22)
#undef STORE
}

extern "C" __global__ void __launch_bounds__(256, 8)
logm_kernel(const float* __restrict__ x, float* __restrict__ y)
{
    int t = blockIdx.x * blockDim.x + threadIdx.x;     // < 524288
    int v = t << 1;                                    // voxel pair, batch 0 & 1
    const float* xb0 = x + v;                          // batch 0
    const float* xb1 = x + 9 * (size_t)NV + v;         // batch 1
    float* yb0 = y + v;
    float* yb1 = y + 9 * (size_t)NV + v;

    // issue ALL loads up front: stage-B latency hides under stage-A compute
    float2 A0[6], A1[6];
    const int plane[6] = {0, 1, 2, 4, 5, 8};
#pragma unroll
    for (int k = 0; k < 6; ++k)
        A0[k] = *reinterpret_cast<const float2*>(xb0 + (size_t)plane[k] * NV);
#pragma unroll
    for (int k = 0; k < 6; ++k)
        A1[k] = *reinterpret_cast<const float2*>(xb1 + (size_t)plane[k] * NV);

    stage(A0, yb0);   // stores drain under stage-B compute
    stage(A1, yb1);
}

extern "C" void kernel_launch(void* const* d_in, const int* in_sizes, int n_in,
                              void* d_out, int out_size, void* d_ws, size_t ws_size,
                              hipStream_t stream) {
    const float* x = (const float*)d_in[0];
    float*       y = (float*)d_out;
    const int total_threads = NV / 2;                  // 524288 (each does 2 batches)
    dim3 grid(total_threads / 256), block(256);
    hipLaunchKernelGGL(logm_kernel, grid, block, 0, stream, x, y);
}

// Round 11
// 27.179 us; speedup vs baseline: 1.0334x; 1.0334x over previous
//
#include <hip/hip_runtime.h>

// Logm of 2*2^20 independent 3x3 SPD matrices — closed-form eigenvalues.
// Layout: x[b][c][v], c = 3*i+j, plane stride NV = 2^20 floats.
// Input is bit-symmetric -> read only upper-triangle planes {0,1,2,4,5,8}.
// r9 structure (float4, 4 voxels/tile) + 2-tile/thread software pipeline:
// tile A = voxels [4t,4t+4) batch 0, tile B = same voxels batch 1. All 12
// float4 loads issued up front; compute-A waits only vmcnt(6) so B's loads
// stay in flight; A's stores drain under B's compute. Defeats the global
// lockstep (identical blocks -> machine-wide load/compute phase alternation)
// that made r9 additive (26.6 = 16 mem + 10.6 VALU).
// Per voxel: char-poly -> Cardano trig eigenvalues -> Newton divided
// differences: log(M) = k0*I + k1*M + k2*M^2 (passed r8/r9/r10).

#define NV (1 << 20)   // D*H*W
#define BT 2

__device__ __forceinline__ float rcpf(float x) { return __builtin_amdgcn_rcpf(x); }

__device__ __forceinline__ void logm3(
    float a00, float a01, float a02, float a11, float a12, float a22,
    float &y00, float &y01, float &y02, float &y11, float &y12, float &y22)
{
    const float THIRD = 0.33333333333f;
    float m   = (a00 + a11 + a22) * THIRD;
    float b00 = a00 - m, b11 = a11 - m, b22 = a22 - m;
    float off2  = fmaf(a01, a01, fmaf(a02, a02, a12 * a12));
    float diag2 = fmaf(b00, b00, fmaf(b11, b11, b22 * b22));
    float p2 = fmaf(diag2, 1.0f / 6.0f, off2 * THIRD);   // p = tr(B^2)/6
    float sp = sqrtf(p2);
    float detB = b00 * fmaf(b11, b22, -a12 * a12)
               - a01 * fmaf(a01, b22, -a12 * a02)
               + a02 * fmaf(a01, a12, -b11 * a02);
    float q  = 0.5f * detB;
    float rr = q * rcpf(fmaxf(p2 * sp, 1e-30f));         // q / p^(3/2)
    rr = fminf(fmaxf(rr, -1.0f), 1.0f);

    // acos(rr): deg-7 poly on |rr|, reflect for rr<0  (|err| ~ 7e-8 rad)
    float ar  = fabsf(rr);
    float acp = fmaf(ar, fmaf(ar, fmaf(ar, fmaf(ar, fmaf(ar, fmaf(ar, fmaf(ar,
        -0.0012624911f, 0.0066700901f), -0.0170881256f), 0.0308918810f),
        -0.0501743046f), 0.0889789874f), -0.2145988016f), 1.5707963050f);
    float A   = sqrtf(fmaxf(1.0f - ar, 0.0f)) * acp;
    float phi = (rr >= 0.0f) ? A : (3.14159265359f - A);
    float th  = phi * THIRD;                              // [0, pi/3]

    float c0  = __cosf(th);
    float s0  = sqrtf(fmaxf(fmaf(-c0, c0, 1.0f), 0.0f));
    float cm  = -0.5f * c0;
    float c1  = fmaf(-0.86602540378f, s0, cm);            // -> min
    float c2c = fmaf( 0.86602540378f, s0, cm);            // -> mid
    float tsp = 2.0f * sp;
    float L1 = fmaf(tsp, c0,  m);                         // max
    float L2 = fmaf(tsp, c2c, m);                         // mid
    float L3 = fmaf(tsp, c1,  m);                         // min

    float g1 = __logf(L1), g2 = __logf(L2), g3 = __logf(L3);

    float d12 = L1 - L2, d23 = L2 - L3;
    float d13 = fmaxf(L1 - L3, 1e-6f);
    float i2  = rcpf(L2), i3 = rcpf(L3);
    float x12 = d12 * i2, x23 = d23 * i3;
    float s12 = fmaf(x12, fmaf(x12, fmaf(x12, -0.25f, THIRD), -0.5f), 1.0f);
    float s23 = fmaf(x23, fmaf(x23, fmaf(x23, -0.25f, THIRD), -0.5f), 1.0f);
    float f12 = (x12 < 0.03f) ? s12 * i2 : (g1 - g2) * rcpf(fmaxf(d12, 1e-30f));
    float f23 = (x23 < 0.03f) ? s23 * i3 : (g2 - g3) * rcpf(fmaxf(d23, 1e-30f));
    float cc2 = (f12 - f23) * rcpf(d13);

    float k0 = fmaf(cc2, L1 * L2, fmaf(-f12, L1, g1));
    float k1 = fmaf(-cc2, L1 + L2, f12);

    float s00  = fmaf(a00, a00, fmaf(a01, a01, a02 * a02));
    float s11  = fmaf(a01, a01, fmaf(a11, a11, a12 * a12));
    float s22  = fmaf(a02, a02, fmaf(a12, a12, a22 * a22));
    float s01  = fmaf(a01, a00 + a11, a02 * a12);
    float s02  = fmaf(a02, a00 + a22, a01 * a12);
    float s12m = fmaf(a12, a11 + a22, a01 * a02);

    y00 = fmaf(cc2, s00,  fmaf(k1, a00, k0));
    y11 = fmaf(cc2, s11,  fmaf(k1, a11, k0));
    y22 = fmaf(cc2, s22,  fmaf(k1, a22, k0));
    y01 = fmaf(cc2, s01,  k1 * a01);
    y02 = fmaf(cc2, s02,  k1 * a02);
    y12 = fmaf(cc2, s12m, k1 * a12);
}

// compute 4 voxels from 6 float4 plane-vectors, store 9 float4 planes
__device__ __forceinline__ void stage(
    const float4 &A00, const float4 &A01, const float4 &A02,
    const float4 &A11, const float4 &A12, const float4 &A22, float* yb)
{
    float a00[4] = {A00.x, A00.y, A00.z, A00.w};
    float a01[4] = {A01.x, A01.y, A01.z, A01.w};
    float a02[4] = {A02.x, A02.y, A02.z, A02.w};
    float a11[4] = {A11.x, A11.y, A11.z, A11.w};
    float a12[4] = {A12.x, A12.y, A12.z, A12.w};
    float a22[4] = {A22.x, A22.y, A22.z, A22.w};

    float O00[4], O01[4], O02[4], O11[4], O12[4], O22[4];
#pragma unroll
    for (int j = 0; j < 4; ++j)
        logm3(a00[j], a01[j], a02[j], a11[j], a12[j], a22[j],
              O00[j], O01[j], O02[j], O11[j], O12[j], O22[j]);

    float4 W;
#define STORE(ch, arr) \
    W.x = arr[0]; W.y = arr[1]; W.z = arr[2]; W.w = arr[3]; \
    *reinterpret_cast<float4*>(yb + (size_t)(ch) * NV) = W;
    STORE(0, O00) STORE(1, O01) STORE(2, O02)
    STORE(3, O01) STORE(4, O11) STORE(5, O12)
    STORE(6, O02) STORE(7, O12) STORE(8, O22)
#undef STORE
}

extern "C" __global__ void __launch_bounds__(256, 4)
logm_kernel(const float* __restrict__ x, float* __restrict__ y)
{
    int t = blockIdx.x * blockDim.x + threadIdx.x;     // < 262144
    int v = t << 2;                                    // 4 voxels, batches 0 & 1
    const float* xa = x + v;                           // batch 0
    const float* xb = x + 9 * (size_t)NV + v;          // batch 1
    float* ya = y + v;
    float* yb = y + 9 * (size_t)NV + v;

    // issue ALL 12 loads up front; compute-A only needs vmcnt(6)
    float4 A00 = *reinterpret_cast<const float4*>(xa + 0 * (size_t)NV);
    float4 A01 = *reinterpret_cast<const float4*>(xa + 1 * (size_t)NV);
    float4 A02 = *reinterpret_cast<const float4*>(xa + 2 * (size_t)NV);
    float4 A11 = *reinterpret_cast<const float4*>(xa + 4 * (size_t)NV);
    float4 A12 = *reinterpret_cast<const float4*>(xa + 5 * (size_t)NV);
    float4 A22 = *reinterpret_cast<const float4*>(xa + 8 * (size_t)NV);
    float4 B00 = *reinterpret_cast<const float4*>(xb + 0 * (size_t)NV);
    float4 B01 = *reinterpret_cast<const float4*>(xb + 1 * (size_t)NV);
    float4 B02 = *reinterpret_cast<const float4*>(xb + 2 * (size_t)NV);
    float4 B11 = *reinterpret_cast<const float4*>(xb + 4 * (size_t)NV);
    float4 B12 = *reinterpret_cast<const float4*>(xb + 5 * (size_t)NV);
    float4 B22 = *reinterpret_cast<const float4*>(xb + 8 * (size_t)NV);

    stage(A00, A01, A02, A11, A12, A22, ya);  // B loads in flight during this
    stage(B00, B01, B02, B11, B12, B22, yb);  // A stores drain during this
}

extern "C" void kernel_launch(void* const* d_in, const int* in_sizes, int n_in,
                              void* d_out, int out_size, void* d_ws, size_t ws_size,
                              hipStream_t stream) {
    const float* x = (const float*)d_in[0];
    float*       y = (float*)d_out;
    const int total_threads = NV / 4;                  // 262144 (8 voxels/thread)
    dim3 grid(total_threads / 256), block(256);
    hipLaunchKernelGGL(logm_kernel, grid, block, 0, stream, x, y);
}